// Round 14
// baseline (134.413 us; speedup 1.0000x reference)
//
#include <hip/hip_runtime.h>

#define KDIM    1200
#define NBITS   2400
#define BATCHN  16384
#define NPAR    1200
#define KP      1216            // K padded to 19*64
#define KSL     19              // 64-wide k-slices
// fallback-path constants
#define WPAD    20
#define ROWS    16

typedef int i32x4 __attribute__((ext_vector_type(4)));

// ---------- conv_m: m int32 -> A_i8 [BATCHN][KP] + identity half of out ----------
__global__ __launch_bounds__(256) void conv_m(const int* __restrict__ m,
                                              unsigned char* __restrict__ A,
                                              float* __restrict__ out) {
    int gid = blockIdx.x * 256 + threadIdx.x;     // BATCHN*304 threads, exact
    int row = gid / 304;
    int seg = gid - row * 304;                    // dword index within padded row
    unsigned char* ap = A + (size_t)row * KP + seg * 4;
    if (seg < 300) {
        int4 v = *(const int4*)(m + (size_t)row * KDIM + seg * 4);
        unsigned b0 = v.x != 0, b1 = v.y != 0, b2 = v.z != 0, b3 = v.w != 0;
        *(unsigned*)ap = b0 | (b1 << 8) | (b2 << 16) | (b3 << 24);
        float4 f;
        f.x = __uint_as_float(0x3f800000u | (b0 << 31));
        f.y = __uint_as_float(0x3f800000u | (b1 << 31));
        f.z = __uint_as_float(0x3f800000u | (b2 << 31));
        f.w = __uint_as_float(0x3f800000u | (b3 << 31));
        *(float4*)(out + (size_t)row * NBITS + seg * 4) = f;
    } else {
        *(unsigned*)ap = 0u;                      // K pad
    }
}

// ---------- conv_g: G parity rows (1200..2399) f32 -> Gp_i8 [NPAR][KP] ----------
__global__ __launch_bounds__(256) void conv_g(const float* __restrict__ G,
                                              unsigned char* __restrict__ Bm) {
    int gid = blockIdx.x * 256 + threadIdx.x;     // NPAR*304 threads, exact
    int n   = gid / 304;
    int seg = gid - n * 304;
    unsigned char* bp = Bm + (size_t)n * KP + seg * 4;
    if (seg < 300) {
        float4 v = *(const float4*)(G + (size_t)(NPAR + n) * KDIM + seg * 4);
        unsigned b0 = v.x != 0.0f, b1 = v.y != 0.0f, b2 = v.z != 0.0f, b3 = v.w != 0.0f;
        *(unsigned*)bp = b0 | (b1 << 8) | (b2 << 16) | (b3 << 24);
    } else {
        *(unsigned*)bp = 0u;
    }
}

// ---------- gemm_i8: parity half via MFMA ----------
// grid (256, 3): x = M-panel (64 rows), y = N-panel (400 cols = 25 16-wide tiles).
// N-siblings of an M-panel differ by 256 in dispatch id -> same XCD -> A L2-reuse.
__global__ __launch_bounds__(256, 3) void gemm_i8(const unsigned char* __restrict__ A,
                                                  const unsigned char* __restrict__ Bm,
                                                  float* __restrict__ out) {
    const int l  = threadIdx.x & 63;
    const int w  = threadIdx.x >> 6;              // wave 0..3 -> M sub-tile
    const int by = blockIdx.x;                    // 0..255
    const int bx = blockIdx.y;                    // 0..2

    // A fragments for this wave's 16 rows, all 19 k-slices (76 VGPRs)
    const int rowA = by * 64 + w * 16 + (l & 15);
    const int kof  = (l >> 4) * 16;               // 16-byte k-group within a slice
    const i32x4* ap = (const i32x4*)(A + (size_t)rowA * KP + kof);
    i32x4 a[KSL];
    #pragma unroll
    for (int s = 0; s < KSL; ++s) a[s] = ap[4 * s];

    const int crow0 = by * 64 + w * 16 + (l >> 4) * 4;   // C/D: row=4*(l>>4)+reg
    float* obase = out + (size_t)crow0 * NBITS + NPAR;

    #pragma unroll 1
    for (int t = 0; t < 25; ++t) {
        const int col = bx * 400 + t * 16 + (l & 15);    // C/D + B: col = l&15
        const i32x4* bp = (const i32x4*)(Bm + (size_t)col * KP + kof);
        i32x4 c = {0, 0, 0, 0};
        #pragma unroll 4
        for (int s = 0; s < KSL; ++s)
            c = __builtin_amdgcn_mfma_i32_16x16x64_i8(a[s], bp[4 * s], c, 0, 0, 0);
        #pragma unroll
        for (int r = 0; r < 4; ++r)
            obase[(size_t)r * NBITS + col] =
                __uint_as_float(0x3f800000u | ((unsigned)(c[r] & 1) << 31));
    }
}

// ============== fallback bit-slice path (r7-proven) ==============

__global__ __launch_bounds__(256) void pack_rows_int(const int* __restrict__ src,
                                                     unsigned long long* __restrict__ dst) {
    int gtid = blockIdx.x * blockDim.x + threadIdx.x;
    int wave = gtid >> 6, lane = gtid & 63;
    if (wave >= BATCHN) return;
    const int* row = src + (size_t)wave * KDIM;
    unsigned long long* orow = dst + (size_t)wave * WPAD;
    #pragma unroll
    for (int j = 0; j < WPAD; ++j) {
        int idx = j * 64 + lane;
        int v = (idx < KDIM) ? row[idx] : 0;
        unsigned long long mask = __ballot(v != 0);
        if (lane == 0) orow[j] = mask;
    }
}

__global__ __launch_bounds__(256) void pack_g(const float* __restrict__ G,
                                              unsigned long long* __restrict__ gp) {
    int gtid = blockIdx.x * blockDim.x + threadIdx.x;
    int wave = gtid >> 6, lane = gtid & 63;
    if (wave >= NPAR) return;
    const float* row = G + (size_t)(NPAR + wave) * KDIM;
    unsigned long long* orow = gp + (size_t)wave * WPAD;
    #pragma unroll
    for (int j = 0; j < WPAD; ++j) {
        int idx = j * 64 + lane;
        float v = (idx < KDIM) ? row[idx] : 0.0f;
        unsigned long long mask = __ballot(v != 0.0f);
        if (lane == 0) orow[j] = mask;
    }
}

__global__ __launch_bounds__(256, 4) void ldpc_encode_fb(const unsigned long long* __restrict__ mp,
                                                         const unsigned long long* __restrict__ gp,
                                                         float* __restrict__ out) {
    const int tid = threadIdx.x;
    const int n   = blockIdx.x * 256 + tid;
    const bool nv = (n < NPAR);
    unsigned g[38];
    {
        const uint4* gr = (const uint4*)(gp + (size_t)(nv ? n : 0) * WPAD);
        #pragma unroll
        for (int j = 0; j < 9; ++j) {
            uint4 v = gr[j];
            g[4*j] = v.x; g[4*j+1] = v.y; g[4*j+2] = v.z; g[4*j+3] = v.w;
        }
        uint4 v9 = gr[9];
        g[36] = v9.x; g[37] = v9.y;
    }
    const int row0 = blockIdx.y * ROWS;
    const uint4* mr = (const uint4*)(mp + (size_t)row0 * WPAD);
    const int idw = blockIdx.x * 8 + (tid >> 5);
    float* ob = out + (size_t)row0 * NBITS;
    #pragma unroll 1
    for (int i = 0; i < ROWS; ++i) {
        uint4 t[10];
        #pragma unroll
        for (int j = 0; j < 10; ++j) t[j] = mr[j];
        unsigned idb = ((const unsigned*)mr)[idw];
        unsigned p = 0;
        #pragma unroll
        for (int j = 0; j < 9; ++j) {
            p ^= t[j].x & g[4*j];
            p ^= t[j].y & g[4*j+1];
            p ^= t[j].z & g[4*j+2];
            p ^= t[j].w & g[4*j+3];
        }
        p ^= t[9].x & g[36];
        p ^= t[9].y & g[37];
        if (nv) {
            ob[n]        = __uint_as_float(0x3f800000u | (((idb >> (tid & 31)) & 1u) << 31));
            ob[NPAR + n] = __uint_as_float(0x3f800000u | ((unsigned)__popc(p) << 31));
        }
        mr += WPAD / 2;
        ob += NBITS;
    }
}

__global__ __launch_bounds__(256) void ldpc_naive(const int* __restrict__ m,
                                                  const float* __restrict__ G,
                                                  float* __restrict__ out) {
    long long idx = (long long)blockIdx.x * blockDim.x + threadIdx.x;
    if (idx >= (long long)BATCHN * NBITS) return;
    int b = (int)(idx / NBITS);
    int n = (int)(idx % NBITS);
    int acc = 0;
    const int*   mr = m + (size_t)b * KDIM;
    const float* gr = G + (size_t)n * KDIM;
    for (int k = 0; k < KDIM; ++k)
        acc ^= (mr[k] & (gr[k] != 0.0f ? 1 : 0));
    out[idx] = 1.0f - 2.0f * (float)acc;
}

// ============== launcher ==============

extern "C" void kernel_launch(void* const* d_in, const int* in_sizes, int n_in,
                              void* d_out, int out_size, void* d_ws, size_t ws_size,
                              hipStream_t stream) {
    const int*   m = (const int*)d_in[0];    // [BATCHN, KDIM] int32 (0/1)
    const float* G = (const float*)d_in[1];  // [NBITS, KDIM]  f32, top 1200x1200 = I
    float* out = (float*)d_out;              // [BATCHN, NBITS] f32

    const size_t sz_A  = (size_t)BATCHN * KP;            // 19,922,944
    const size_t sz_B  = (size_t)NPAR * KP;              //  1,459,200
    const size_t need_mfma = sz_A + sz_B;                // ~20.4 MiB
    const size_t need_fb = ((size_t)BATCHN + NPAR) * WPAD * sizeof(unsigned long long);

    if (ws_size >= need_mfma) {
        unsigned char* A  = (unsigned char*)d_ws;
        unsigned char* Bm = A + sz_A;

        conv_g<<<(NPAR * 304) / 256, 256, 0, stream>>>(G, Bm);
        conv_m<<<(BATCHN * 304) / 256, 256, 0, stream>>>(m, A, out);
        dim3 grid(BATCHN / 64, 3);                       // (256, 3)
        gemm_i8<<<grid, 256, 0, stream>>>(A, Bm, out);
    } else if (ws_size >= need_fb) {
        unsigned long long* mp = (unsigned long long*)d_ws;
        unsigned long long* gp = mp + (size_t)BATCHN * WPAD;
        pack_g       <<<(NPAR * 64) / 256, 256, 0, stream>>>(G, gp);
        pack_rows_int<<<(BATCHN * 64) / 256, 256, 0, stream>>>(m, mp);
        dim3 grid((NPAR + 255) / 256, BATCHN / ROWS);
        ldpc_encode_fb<<<grid, 256, 0, stream>>>(mp, gp, out);
    } else {
        long long total = (long long)BATCHN * NBITS;
        ldpc_naive<<<(int)((total + 255) / 256), 256, 0, stream>>>(m, G, out);
    }
}